// Round 1
// baseline (1266.071 us; speedup 1.0000x reference)
//
#include <hip/hip_runtime.h>
#include <hip/hip_bf16.h>
#include <math.h>

#define NT 8192        // tokens (B*S)
#define HD 2048        // hidden
#define ID 4096        // intermediate
#define NE 8           // experts
#define MAXSLOT 17408  // 16384 + padding headroom (multiple of 128)
#define MAXRB 136      // MAXSLOT/128

typedef __bf16 bf16x8 __attribute__((ext_vector_type(8)));
typedef float f32x4 __attribute__((ext_vector_type(4)));

__device__ __forceinline__ float bf2f(unsigned short u){
  union{unsigned u; float f;} v; v.u = ((unsigned)u) << 16; return v.f;
}

__device__ __forceinline__ void gload_lds16(const void* g, void* l){
  __builtin_amdgcn_global_load_lds((const __attribute__((address_space(1))) void*)g,
                                   (__attribute__((address_space(3))) void*)l, 16, 0, 0);
}

// ---------- fp32 -> bf16 convert (vectorized) ----------
__global__ __launch_bounds__(256) void cvt_kernel(const float* __restrict__ in,
                                                  __hip_bfloat16* __restrict__ outp, int n4){
  int i = blockIdx.x * blockDim.x + threadIdx.x;
  int stride = gridDim.x * blockDim.x;
  for (; i < n4; i += stride){
    float4 v = reinterpret_cast<const float4*>(in)[i];
    union{ushort4 u; __hip_bfloat16 h[4];} o;
    o.h[0] = __float2bfloat16(v.x); o.h[1] = __float2bfloat16(v.y);
    o.h[2] = __float2bfloat16(v.z); o.h[3] = __float2bfloat16(v.w);
    reinterpret_cast<ushort4*>(outp)[i] = o.u;
  }
}

// ---------- router: fp64 logits, top-2, softmax weights ----------
__global__ __launch_bounds__(256) void router_kernel(
    const float* __restrict__ x, const float* __restrict__ gw,
    float* __restrict__ logits_out, int* __restrict__ tokExp,
    float* __restrict__ tokW, int* __restrict__ cnt)
{
  int wave = (blockIdx.x * blockDim.x + threadIdx.x) >> 6;
  int lane = threadIdx.x & 63;
  if (wave >= NT) return;
  const float* xr = x + (long)wave * HD;
  double acc[NE];
  #pragma unroll
  for (int e = 0; e < NE; e++) acc[e] = 0.0;
  for (int k = lane; k < HD; k += 64){
    double xv = (double)xr[k];
    #pragma unroll
    for (int e = 0; e < NE; e++) acc[e] += xv * (double)gw[e * HD + k];
  }
  #pragma unroll
  for (int e = 0; e < NE; e++){
    #pragma unroll
    for (int off = 32; off; off >>= 1) acc[e] += __shfl_down(acc[e], off, 64);
  }
  if (lane == 0){
    int e0 = 0; double v0 = acc[0];
    for (int e = 1; e < NE; e++) if (acc[e] > v0){ v0 = acc[e]; e0 = e; }
    int e1 = -1; double v1 = -1e300;
    for (int e = 0; e < NE; e++) if (e != e0 && acc[e] > v1){ v1 = acc[e]; e1 = e; }
    double ex = exp(v1 - v0);
    double s = 1.0 + ex;
    for (int e = 0; e < NE; e++) logits_out[wave * NE + e] = (float)acc[e];
    tokExp[wave * 2]     = e0; tokExp[wave * 2 + 1] = e1;
    tokW[wave * 2]       = (float)(1.0 / s);
    tokW[wave * 2 + 1]   = (float)(ex / s);
    atomicAdd(&cnt[e0], 1); atomicAdd(&cnt[e1], 1);
  }
}

// ---------- padded exclusive prefix over expert counts ----------
__global__ void offsets_kernel(const int* __restrict__ cnt, int* __restrict__ padOff){
  if (threadIdx.x == 0 && blockIdx.x == 0){
    int o = 0;
    for (int e = 0; e < NE; e++){ padOff[e] = o; o += ((cnt[e] + 127) >> 7) << 7; }
    padOff[NE] = o;
  }
}

// ---------- scatter tokens into padded per-expert segments ----------
__global__ __launch_bounds__(256) void scatter_kernel(
    const int* __restrict__ tokExp, const float* __restrict__ tokW,
    const int* __restrict__ padOff, int* cursor,
    int* __restrict__ slotTok, int* __restrict__ tokSlot)
{
  int t = blockIdx.x * blockDim.x + threadIdx.x;
  if (t >= NT) return;
  #pragma unroll
  for (int s = 0; s < 2; s++){
    int e = tokExp[t * 2 + s];
    int pos = atomicAdd(&cursor[e], 1);
    int slot = padOff[e] + pos;
    slotTok[slot] = t;
    tokSlot[t * 2 + s] = slot;
  }
}

// ---------- grouped GEMM: C[row,col] = A[row,:] . W[e][col,:]  (NT layout) ----------
// EPI=0: h = gelu(acc + bfc)  -> bf16 Yout[slot][ND]
// EPI=1: y = acc + bproj      -> bf16 Yout[slot][ND]
template<int GATHER_A, int EPI, int ND, int KD>
__global__ __launch_bounds__(256, 2) void moe_gemm(
    const __hip_bfloat16* __restrict__ A,
    const float* __restrict__ W,
    const float* __restrict__ bias,
    const int* __restrict__ slotTok,
    const int* __restrict__ padOff,
    __hip_bfloat16* __restrict__ Yout)
{
  __shared__ __hip_bfloat16 As[128 * 32];
  __shared__ __hip_bfloat16 Bs[128 * 32];
  const int rb = blockIdx.y;
  const int total = padOff[NE];
  if (rb * 128 >= total) return;
  const int cb = blockIdx.x;
  int e = 0;
  #pragma unroll
  for (int i = 1; i < NE; i++) if (rb * 128 >= padOff[i]) e = i;

  const int tid  = threadIdx.x;
  const int lane = tid & 63;
  const int w    = tid >> 6;
  const int wr   = w >> 1, wc = w & 1;

  // A staging: wave w issues global_load_lds j=2w, 2w+1 (each: 16 rows x 32 k)
  const int j0  = 2 * w;
  const int ar0 = j0 * 16 + (lane >> 2);
  const int kch = lane & 3;
  long aRow0, aRow1;
  {
    int g0 = rb * 128 + ar0, g1 = g0 + 16;
    if (GATHER_A){
      int t0 = slotTok[g0]; if (t0 < 0) t0 = 0;
      int t1 = slotTok[g1]; if (t1 < 0) t1 = 0;
      aRow0 = t0; aRow1 = t1;
    } else { aRow0 = g0; aRow1 = g1; }
  }
  const __hip_bfloat16* gA0 = A + aRow0 * (long)KD + kch * 8;
  const __hip_bfloat16* gA1 = A + aRow1 * (long)KD + kch * 8;
  __hip_bfloat16* lA0 = &As[j0 * 512];
  __hip_bfloat16* lA1 = &As[j0 * 512 + 512];

  // B staging: fp32 global -> bf16 LDS, 4 float4 per thread
  const float* gB = W + (long)e * ND * KD + ((long)cb * 128 + (tid >> 3)) * KD + (tid & 7) * 4;
  __hip_bfloat16* lB = &Bs[(tid >> 3) * 32 + (tid & 7) * 4];

  // fragment pointers
  const int frow = lane & 15;
  const int fkb  = (lane >> 4) * 8;
  const bf16x8* aP[4]; const bf16x8* bP[4];
  #pragma unroll
  for (int m = 0; m < 4; m++) aP[m] = reinterpret_cast<const bf16x8*>(&As[(wr * 64 + m * 16 + frow) * 32 + fkb]);
  #pragma unroll
  for (int n = 0; n < 4; n++) bP[n] = reinterpret_cast<const bf16x8*>(&Bs[(wc * 64 + n * 16 + frow) * 32 + fkb]);

  f32x4 acc[4][4] = {};

  const int NKS = KD / 32;
  for (int kt = 0; kt < NKS; kt++){
    __syncthreads();
    gload_lds16(gA0 + kt * 32, lA0);
    gload_lds16(gA1 + kt * 32, lA1);
    #pragma unroll
    for (int q = 0; q < 4; q++){
      float4 v = *reinterpret_cast<const float4*>(gB + (long)q * 32 * KD + kt * 32);
      union{ushort4 u; __hip_bfloat16 h[4];} pk;
      pk.h[0] = __float2bfloat16(v.x); pk.h[1] = __float2bfloat16(v.y);
      pk.h[2] = __float2bfloat16(v.z); pk.h[3] = __float2bfloat16(v.w);
      *reinterpret_cast<ushort4*>(lB + q * 32 * 32) = pk.u;
    }
    __syncthreads();
    bf16x8 av[4], bv[4];
    #pragma unroll
    for (int m = 0; m < 4; m++) av[m] = aP[m][0];
    #pragma unroll
    for (int n = 0; n < 4; n++) bv[n] = bP[n][0];
    #pragma unroll
    for (int m = 0; m < 4; m++){
      #pragma unroll
      for (int n = 0; n < 4; n++){
        acc[m][n] = __builtin_amdgcn_mfma_f32_16x16x32_bf16(av[m], bv[n], acc[m][n], 0, 0, 0);
      }
    }
  }

  // epilogue: C layout col=lane&15, row=(lane>>4)*4+reg
  const int col0 = cb * 128 + wc * 64 + frow;
  const int row0 = rb * 128 + wr * 64 + (lane >> 4) * 4;
  #pragma unroll
  for (int n = 0; n < 4; n++){
    const int col = col0 + n * 16;
    const float bb = bias[(long)e * ND + col];
    #pragma unroll
    for (int m = 0; m < 4; m++){
      const long rbase = (long)(row0 + m * 16);
      #pragma unroll
      for (int r = 0; r < 4; r++){
        float v = acc[m][n][r] + bb;
        if (EPI == 0){
          v = 0.5f * v * (1.0f + erff(v * 0.70710678118654752f));  // exact gelu
        }
        Yout[(rbase + r) * ND + col] = __float2bfloat16(v);
      }
    }
  }
}

// ---------- combine: out[t] = w0*y[slot0] + w1*y[slot1] ----------
__global__ __launch_bounds__(256) void combine_kernel(
    const __hip_bfloat16* __restrict__ yb,
    const int* __restrict__ tokSlot, const float* __restrict__ tokW,
    float* __restrict__ outp)
{
  const int t  = blockIdx.x;
  const int c0 = threadIdx.x * 8;
  const int s0 = tokSlot[t * 2], s1 = tokSlot[t * 2 + 1];
  const float w0 = tokW[t * 2], w1 = tokW[t * 2 + 1];
  const ushort4* p0 = reinterpret_cast<const ushort4*>(yb + (long)s0 * HD + c0);
  const ushort4* p1 = reinterpret_cast<const ushort4*>(yb + (long)s1 * HD + c0);
  float4 o[2];
  #pragma unroll
  for (int h = 0; h < 2; h++){
    ushort4 a = p0[h], b = p1[h];
    o[h].x = w0 * bf2f(a.x) + w1 * bf2f(b.x);
    o[h].y = w0 * bf2f(a.y) + w1 * bf2f(b.y);
    o[h].z = w0 * bf2f(a.z) + w1 * bf2f(b.z);
    o[h].w = w0 * bf2f(a.w) + w1 * bf2f(b.w);
  }
  float4* po = reinterpret_cast<float4*>(outp + (long)t * HD + c0);
  po[0] = o[0]; po[1] = o[1];
}

extern "C" void kernel_launch(void* const* d_in, const int* in_sizes, int n_in,
                              void* d_out, int out_size, void* d_ws, size_t ws_size,
                              hipStream_t stream)
{
  (void)in_sizes; (void)n_in; (void)out_size; (void)ws_size;
  const float* x     = (const float*)d_in[0];
  const float* gw    = (const float*)d_in[1];
  const float* wfc   = (const float*)d_in[2];
  const float* bfc   = (const float*)d_in[3];
  const float* wproj = (const float*)d_in[4];
  const float* bproj = (const float*)d_in[5];
  float* outp   = (float*)d_out;
  float* logits = outp + (size_t)NT * HD;

  char* ws = (char*)d_ws;
  size_t off = 0;
  auto alloc = [&](size_t b){ void* p = ws + off; off += (b + 255) & ~(size_t)255; return p; };

  // xb (fc input) and yb (proj output) have disjoint lifetimes -> share region
  char* shared0 = (char*)alloc((size_t)MAXSLOT * HD * 2);   // 71 MB
  __hip_bfloat16* xb = (__hip_bfloat16*)shared0;            // needs 33.5 MB
  __hip_bfloat16* yb = (__hip_bfloat16*)shared0;
  __hip_bfloat16* hb = (__hip_bfloat16*)alloc((size_t)MAXSLOT * ID * 2);  // 142.6 MB
  int*   slotTok = (int*)alloc(MAXSLOT * 4);
  int*   tokExp  = (int*)alloc(NT * 2 * 4);
  float* tokW    = (float*)alloc(NT * 2 * 4);
  int*   tokSlot = (int*)alloc(NT * 2 * 4);
  int*   meta    = (int*)alloc(256);
  int* cnt = meta; int* cursor = meta + 8; int* padOff = meta + 16;

  hipMemsetAsync(meta, 0, 256, stream);
  hipMemsetAsync(slotTok, 0xFF, MAXSLOT * 4, stream);

  cvt_kernel<<<2048, 256, 0, stream>>>(x, xb, NT * HD / 4);
  router_kernel<<<NT / 4, 256, 0, stream>>>(x, gw, logits, tokExp, tokW, cnt);
  offsets_kernel<<<1, 64, 0, stream>>>(cnt, padOff);
  scatter_kernel<<<NT / 256, 256, 0, stream>>>(tokExp, tokW, padOff, cursor, slotTok, tokSlot);
  moe_gemm<1, 0, ID, HD><<<dim3(ID / 128, MAXRB), 256, 0, stream>>>(xb, wfc, bfc, slotTok, padOff, hb);
  moe_gemm<0, 1, HD, ID><<<dim3(HD / 128, MAXRB), 256, 0, stream>>>(hb, wproj, bproj, slotTok, padOff, yb);
  combine_kernel<<<NT, 256, 0, stream>>>(yb, tokSlot, tokW, outp);
}

// Round 2
// 1253.389 us; speedup vs baseline: 1.0101x; 1.0101x over previous
//
#include <hip/hip_runtime.h>
#include <hip/hip_bf16.h>
#include <math.h>

#define NT 8192        // tokens (B*S)
#define HD 2048        // hidden
#define ID 4096        // intermediate
#define NE 8           // experts
#define MAXSLOT 17408  // 16384 + padding headroom (multiple of 128)
#define MAXRB 136      // MAXSLOT/128

typedef __bf16 bf16x8 __attribute__((ext_vector_type(8)));
typedef float f32x4 __attribute__((ext_vector_type(4)));

__device__ __forceinline__ float bf2f(unsigned short u){
  union{unsigned u; float f;} v; v.u = ((unsigned)u) << 16; return v.f;
}

__device__ __forceinline__ void gload_lds16(const void* g, void* l){
  __builtin_amdgcn_global_load_lds((const __attribute__((address_space(1))) void*)g,
                                   (__attribute__((address_space(3))) void*)l, 16, 0, 0);
}

// ---------- fp32 -> bf16 convert (vectorized, grid-stride) ----------
__global__ __launch_bounds__(256) void cvt_kernel(const float* __restrict__ in,
                                                  __hip_bfloat16* __restrict__ outp, int n4){
  int i = blockIdx.x * blockDim.x + threadIdx.x;
  int stride = gridDim.x * blockDim.x;
  for (; i < n4; i += stride){
    float4 v = reinterpret_cast<const float4*>(in)[i];
    union{ushort4 u; __hip_bfloat16 h[4];} o;
    o.h[0] = __float2bfloat16(v.x); o.h[1] = __float2bfloat16(v.y);
    o.h[2] = __float2bfloat16(v.z); o.h[3] = __float2bfloat16(v.w);
    reinterpret_cast<ushort4*>(outp)[i] = o.u;
  }
}

// ---------- router: fp64 logits, top-2, softmax weights ----------
__global__ __launch_bounds__(256) void router_kernel(
    const float* __restrict__ x, const float* __restrict__ gw,
    float* __restrict__ logits_out, int* __restrict__ tokExp,
    float* __restrict__ tokW, int* __restrict__ cnt)
{
  int wave = (blockIdx.x * blockDim.x + threadIdx.x) >> 6;
  int lane = threadIdx.x & 63;
  if (wave >= NT) return;
  const float* xr = x + (long)wave * HD;
  double acc[NE];
  #pragma unroll
  for (int e = 0; e < NE; e++) acc[e] = 0.0;
  for (int k = lane; k < HD; k += 64){
    double xv = (double)xr[k];
    #pragma unroll
    for (int e = 0; e < NE; e++) acc[e] += xv * (double)gw[e * HD + k];
  }
  #pragma unroll
  for (int e = 0; e < NE; e++){
    #pragma unroll
    for (int off = 32; off; off >>= 1) acc[e] += __shfl_down(acc[e], off, 64);
  }
  if (lane == 0){
    int e0 = 0; double v0 = acc[0];
    for (int e = 1; e < NE; e++) if (acc[e] > v0){ v0 = acc[e]; e0 = e; }
    int e1 = -1; double v1 = -1e300;
    for (int e = 0; e < NE; e++) if (e != e0 && acc[e] > v1){ v1 = acc[e]; e1 = e; }
    double ex = exp(v1 - v0);
    double s = 1.0 + ex;
    for (int e = 0; e < NE; e++) logits_out[wave * NE + e] = (float)acc[e];
    tokExp[wave * 2]     = e0; tokExp[wave * 2 + 1] = e1;
    tokW[wave * 2]       = (float)(1.0 / s);
    tokW[wave * 2 + 1]   = (float)(ex / s);
    atomicAdd(&cnt[e0], 1); atomicAdd(&cnt[e1], 1);
  }
}

// ---------- padded exclusive prefix over expert counts ----------
__global__ void offsets_kernel(const int* __restrict__ cnt, int* __restrict__ padOff){
  if (threadIdx.x == 0 && blockIdx.x == 0){
    int o = 0;
    for (int e = 0; e < NE; e++){ padOff[e] = o; o += ((cnt[e] + 127) >> 7) << 7; }
    padOff[NE] = o;
  }
}

// ---------- scatter tokens into padded per-expert segments ----------
__global__ __launch_bounds__(256) void scatter_kernel(
    const int* __restrict__ tokExp, const float* __restrict__ tokW,
    const int* __restrict__ padOff, int* cursor,
    int* __restrict__ slotTok, int* __restrict__ tokSlot)
{
  int t = blockIdx.x * blockDim.x + threadIdx.x;
  if (t >= NT) return;
  #pragma unroll
  for (int s = 0; s < 2; s++){
    int e = tokExp[t * 2 + s];
    int pos = atomicAdd(&cursor[e], 1);
    int slot = padOff[e] + pos;
    slotTok[slot] = t;
    tokSlot[t * 2 + s] = slot;
  }
}

// ---------- grouped GEMM, bf16 weights, both operands via global_load_lds ----------
// C[row,col] = A[row,:] . W[e][col,:]
// EPI=0: h = gelu(acc + bfc)  -> bf16 Yout[slot][ND]
// EPI=1: y = acc + bproj      -> bf16 Yout[slot][ND]
template<int GATHER_A, int EPI, int ND, int KD>
__global__ __launch_bounds__(256, 4) void moe_gemm_bf(
    const __hip_bfloat16* __restrict__ A,
    const __hip_bfloat16* __restrict__ W,   // bf16 [NE][ND][KD]
    const float* __restrict__ bias,
    const int* __restrict__ slotTok,
    const int* __restrict__ padOff,
    __hip_bfloat16* __restrict__ Yout)
{
  __shared__ __hip_bfloat16 As[128 * 32];
  __shared__ __hip_bfloat16 Bs[128 * 32];
  const int rb = blockIdx.y;
  const int total = padOff[NE];
  if (rb * 128 >= total) return;
  const int cb = blockIdx.x;
  int e = 0;
  #pragma unroll
  for (int i = 1; i < NE; i++) if (rb * 128 >= padOff[i]) e = i;

  const int tid  = threadIdx.x;
  const int lane = tid & 63;
  const int w    = tid >> 6;
  const int wr   = w >> 1, wc = w & 1;

  // staging geometry: wave w stages rows [j0*16, j0*16+32) of each operand tile.
  // gload_lds: per-lane GLOBAL addr, wave-uniform LDS base + lane*16B.
  // lane -> (row = lane>>2, 16B chunk = lane&3) within a 16-row group.
  const int j0  = 2 * w;
  const int ar0 = j0 * 16 + (lane >> 2);
  const int kch = lane & 3;
  long aRow0, aRow1;
  {
    int g0 = rb * 128 + ar0, g1 = g0 + 16;
    if (GATHER_A){
      int t0 = slotTok[g0]; if (t0 < 0) t0 = 0;
      int t1 = slotTok[g1]; if (t1 < 0) t1 = 0;
      aRow0 = t0; aRow1 = t1;
    } else { aRow0 = g0; aRow1 = g1; }
  }
  const __hip_bfloat16* gA0 = A + aRow0 * (long)KD + kch * 8;
  const __hip_bfloat16* gA1 = A + aRow1 * (long)KD + kch * 8;
  __hip_bfloat16* lA0 = &As[j0 * 512];
  __hip_bfloat16* lA1 = &As[j0 * 512 + 512];

  const long bRow0 = (long)cb * 128 + ar0;
  const __hip_bfloat16* gB0 = W + (long)e * ND * KD + bRow0 * KD + kch * 8;
  const __hip_bfloat16* gB1 = gB0 + 16 * (long)KD;
  __hip_bfloat16* lB0 = &Bs[j0 * 512];
  __hip_bfloat16* lB1 = &Bs[j0 * 512 + 512];

  // fragment pointers
  const int frow = lane & 15;
  const int fkb  = (lane >> 4) * 8;
  const bf16x8* aP[4]; const bf16x8* bP[4];
  #pragma unroll
  for (int m = 0; m < 4; m++) aP[m] = reinterpret_cast<const bf16x8*>(&As[(wr * 64 + m * 16 + frow) * 32 + fkb]);
  #pragma unroll
  for (int n = 0; n < 4; n++) bP[n] = reinterpret_cast<const bf16x8*>(&Bs[(wc * 64 + n * 16 + frow) * 32 + fkb]);

  f32x4 acc[4][4] = {};

  const int NKS = KD / 32;
  for (int kt = 0; kt < NKS; kt++){
    __syncthreads();
    gload_lds16(gA0 + kt * 32, lA0);
    gload_lds16(gA1 + kt * 32, lA1);
    gload_lds16(gB0 + kt * 32, lB0);
    gload_lds16(gB1 + kt * 32, lB1);
    __syncthreads();
    bf16x8 av[4], bv[4];
    #pragma unroll
    for (int m = 0; m < 4; m++) av[m] = aP[m][0];
    #pragma unroll
    for (int n = 0; n < 4; n++) bv[n] = bP[n][0];
    #pragma unroll
    for (int m = 0; m < 4; m++){
      #pragma unroll
      for (int n = 0; n < 4; n++){
        acc[m][n] = __builtin_amdgcn_mfma_f32_16x16x32_bf16(av[m], bv[n], acc[m][n], 0, 0, 0);
      }
    }
  }

  // epilogue: C layout col=lane&15, row=(lane>>4)*4+reg
  const int col0 = cb * 128 + wc * 64 + frow;
  const int row0 = rb * 128 + wr * 64 + (lane >> 4) * 4;
  #pragma unroll
  for (int n = 0; n < 4; n++){
    const int col = col0 + n * 16;
    const float bb = bias[(long)e * ND + col];
    #pragma unroll
    for (int m = 0; m < 4; m++){
      const long rbase = (long)(row0 + m * 16);
      #pragma unroll
      for (int r = 0; r < 4; r++){
        float v = acc[m][n][r] + bb;
        if (EPI == 0){
          v = 0.5f * v * (1.0f + erff(v * 0.70710678118654752f));  // exact gelu
        }
        Yout[(rbase + r) * ND + col] = __float2bfloat16(v);
      }
    }
  }
}

// ---------- fallback grouped GEMM with inline fp32->bf16 B conversion ----------
template<int GATHER_A, int EPI, int ND, int KD>
__global__ __launch_bounds__(256, 2) void moe_gemm_f32(
    const __hip_bfloat16* __restrict__ A,
    const float* __restrict__ W,
    const float* __restrict__ bias,
    const int* __restrict__ slotTok,
    const int* __restrict__ padOff,
    __hip_bfloat16* __restrict__ Yout)
{
  __shared__ __hip_bfloat16 As[128 * 32];
  __shared__ __hip_bfloat16 Bs[128 * 32];
  const int rb = blockIdx.y;
  const int total = padOff[NE];
  if (rb * 128 >= total) return;
  const int cb = blockIdx.x;
  int e = 0;
  #pragma unroll
  for (int i = 1; i < NE; i++) if (rb * 128 >= padOff[i]) e = i;

  const int tid  = threadIdx.x;
  const int lane = tid & 63;
  const int w    = tid >> 6;
  const int wr   = w >> 1, wc = w & 1;

  const int j0  = 2 * w;
  const int ar0 = j0 * 16 + (lane >> 2);
  const int kch = lane & 3;
  long aRow0, aRow1;
  {
    int g0 = rb * 128 + ar0, g1 = g0 + 16;
    if (GATHER_A){
      int t0 = slotTok[g0]; if (t0 < 0) t0 = 0;
      int t1 = slotTok[g1]; if (t1 < 0) t1 = 0;
      aRow0 = t0; aRow1 = t1;
    } else { aRow0 = g0; aRow1 = g1; }
  }
  const __hip_bfloat16* gA0 = A + aRow0 * (long)KD + kch * 8;
  const __hip_bfloat16* gA1 = A + aRow1 * (long)KD + kch * 8;
  __hip_bfloat16* lA0 = &As[j0 * 512];
  __hip_bfloat16* lA1 = &As[j0 * 512 + 512];

  const float* gB = W + (long)e * ND * KD + ((long)cb * 128 + (tid >> 3)) * KD + (tid & 7) * 4;
  __hip_bfloat16* lB = &Bs[(tid >> 3) * 32 + (tid & 7) * 4];

  const int frow = lane & 15;
  const int fkb  = (lane >> 4) * 8;
  const bf16x8* aP[4]; const bf16x8* bP[4];
  #pragma unroll
  for (int m = 0; m < 4; m++) aP[m] = reinterpret_cast<const bf16x8*>(&As[(wr * 64 + m * 16 + frow) * 32 + fkb]);
  #pragma unroll
  for (int n = 0; n < 4; n++) bP[n] = reinterpret_cast<const bf16x8*>(&Bs[(wc * 64 + n * 16 + frow) * 32 + fkb]);

  f32x4 acc[4][4] = {};

  const int NKS = KD / 32;
  for (int kt = 0; kt < NKS; kt++){
    __syncthreads();
    gload_lds16(gA0 + kt * 32, lA0);
    gload_lds16(gA1 + kt * 32, lA1);
    #pragma unroll
    for (int q = 0; q < 4; q++){
      float4 v = *reinterpret_cast<const float4*>(gB + (long)q * 32 * KD + kt * 32);
      union{ushort4 u; __hip_bfloat16 h[4];} pk;
      pk.h[0] = __float2bfloat16(v.x); pk.h[1] = __float2bfloat16(v.y);
      pk.h[2] = __float2bfloat16(v.z); pk.h[3] = __float2bfloat16(v.w);
      *reinterpret_cast<ushort4*>(lB + q * 32 * 32) = pk.u;
    }
    __syncthreads();
    bf16x8 av[4], bv[4];
    #pragma unroll
    for (int m = 0; m < 4; m++) av[m] = aP[m][0];
    #pragma unroll
    for (int n = 0; n < 4; n++) bv[n] = bP[n][0];
    #pragma unroll
    for (int m = 0; m < 4; m++){
      #pragma unroll
      for (int n = 0; n < 4; n++){
        acc[m][n] = __builtin_amdgcn_mfma_f32_16x16x32_bf16(av[m], bv[n], acc[m][n], 0, 0, 0);
      }
    }
  }

  const int col0 = cb * 128 + wc * 64 + frow;
  const int row0 = rb * 128 + wr * 64 + (lane >> 4) * 4;
  #pragma unroll
  for (int n = 0; n < 4; n++){
    const int col = col0 + n * 16;
    const float bb = bias[(long)e * ND + col];
    #pragma unroll
    for (int m = 0; m < 4; m++){
      const long rbase = (long)(row0 + m * 16);
      #pragma unroll
      for (int r = 0; r < 4; r++){
        float v = acc[m][n][r] + bb;
        if (EPI == 0){
          v = 0.5f * v * (1.0f + erff(v * 0.70710678118654752f));
        }
        Yout[(rbase + r) * ND + col] = __float2bfloat16(v);
      }
    }
  }
}

// ---------- combine: out[t] = w0*y[slot0] + w1*y[slot1] ----------
__global__ __launch_bounds__(256) void combine_kernel(
    const __hip_bfloat16* __restrict__ yb,
    const int* __restrict__ tokSlot, const float* __restrict__ tokW,
    float* __restrict__ outp)
{
  const int t  = blockIdx.x;
  const int c0 = threadIdx.x * 8;
  const int s0 = tokSlot[t * 2], s1 = tokSlot[t * 2 + 1];
  const float w0 = tokW[t * 2], w1 = tokW[t * 2 + 1];
  const ushort4* p0 = reinterpret_cast<const ushort4*>(yb + (long)s0 * HD + c0);
  const ushort4* p1 = reinterpret_cast<const ushort4*>(yb + (long)s1 * HD + c0);
  float4 o[2];
  #pragma unroll
  for (int h = 0; h < 2; h++){
    ushort4 a = p0[h], b = p1[h];
    o[h].x = w0 * bf2f(a.x) + w1 * bf2f(b.x);
    o[h].y = w0 * bf2f(a.y) + w1 * bf2f(b.y);
    o[h].z = w0 * bf2f(a.z) + w1 * bf2f(b.z);
    o[h].w = w0 * bf2f(a.w) + w1 * bf2f(b.w);
  }
  float4* po = reinterpret_cast<float4*>(outp + (long)t * HD + c0);
  po[0] = o[0]; po[1] = o[1];
}

extern "C" void kernel_launch(void* const* d_in, const int* in_sizes, int n_in,
                              void* d_out, int out_size, void* d_ws, size_t ws_size,
                              hipStream_t stream)
{
  (void)in_sizes; (void)n_in; (void)out_size;
  const float* x     = (const float*)d_in[0];
  const float* gw    = (const float*)d_in[1];
  const float* wfc   = (const float*)d_in[2];
  const float* bfc   = (const float*)d_in[3];
  const float* wproj = (const float*)d_in[4];
  const float* bproj = (const float*)d_in[5];
  float* outp   = (float*)d_out;
  float* logits = outp + (size_t)NT * HD;

  char* ws = (char*)d_ws;
  size_t off = 0;
  auto alloc = [&](size_t b){ void* p = ws + off; off += (b + 255) & ~(size_t)255; return p; };

  // xb (fc input) and yb (proj output) have disjoint lifetimes -> share region
  char* shared0 = (char*)alloc((size_t)MAXSLOT * HD * 2);               // 71 MB
  __hip_bfloat16* xb = (__hip_bfloat16*)shared0;
  __hip_bfloat16* yb = (__hip_bfloat16*)shared0;
  __hip_bfloat16* hb = (__hip_bfloat16*)alloc((size_t)MAXSLOT * ID * 2); // 142.6 MB
  int*   slotTok = (int*)alloc(MAXSLOT * 4);
  int*   tokExp  = (int*)alloc(NT * 2 * 4);
  float* tokW    = (float*)alloc(NT * 2 * 4);
  int*   tokSlot = (int*)alloc(NT * 2 * 4);
  int*   meta    = (int*)alloc(256);
  int* cnt = meta; int* cursor = meta + 8; int* padOff = meta + 16;

  // single 134 MB bf16 weight buffer, reused: wfcB (fc GEMM) then wprojB (proj GEMM)
  const size_t WB_BYTES = (size_t)NE * ID * HD * 2;
  __hip_bfloat16* wB = (__hip_bfloat16*)(ws + off);
  const bool pre = (off + WB_BYTES) <= ws_size;

  hipMemsetAsync(meta, 0, 256, stream);
  hipMemsetAsync(slotTok, 0xFF, MAXSLOT * 4, stream);

  cvt_kernel<<<2048, 256, 0, stream>>>(x, xb, NT * HD / 4);
  router_kernel<<<NT / 4, 256, 0, stream>>>(x, gw, logits, tokExp, tokW, cnt);
  offsets_kernel<<<1, 64, 0, stream>>>(cnt, padOff);
  scatter_kernel<<<NT / 256, 256, 0, stream>>>(tokExp, tokW, padOff, cursor, slotTok, tokSlot);

  if (pre){
    cvt_kernel<<<2048, 256, 0, stream>>>(wfc, wB, NE * ID * HD / 4);
    moe_gemm_bf<1, 0, ID, HD><<<dim3(ID / 128, MAXRB), 256, 0, stream>>>(xb, wB, bfc, slotTok, padOff, hb);
    cvt_kernel<<<2048, 256, 0, stream>>>(wproj, wB, NE * HD * ID / 4);
    moe_gemm_bf<0, 1, HD, ID><<<dim3(HD / 128, MAXRB), 256, 0, stream>>>(hb, wB, bproj, slotTok, padOff, yb);
  } else {
    moe_gemm_f32<1, 0, ID, HD><<<dim3(ID / 128, MAXRB), 256, 0, stream>>>(xb, wfc, bfc, slotTok, padOff, hb);
    moe_gemm_f32<0, 1, HD, ID><<<dim3(HD / 128, MAXRB), 256, 0, stream>>>(hb, wproj, bproj, slotTok, padOff, yb);
  }

  combine_kernel<<<NT, 256, 0, stream>>>(yb, tokSlot, tokW, outp);
}

// Round 4
// 1230.485 us; speedup vs baseline: 1.0289x; 1.0186x over previous
//
#include <hip/hip_runtime.h>
#include <hip/hip_bf16.h>
#include <math.h>

#define NT 8192        // tokens (B*S)
#define HD 2048        // hidden
#define ID 4096        // intermediate
#define NE 8           // experts
#define MAXSLOT 18432  // per-expert segments padded to 256; sum <= 16384+8*255 -> 18432
#define MAXRB 72       // MAXSLOT/256

typedef __bf16 bf16x8 __attribute__((ext_vector_type(8)));
typedef float f32x4 __attribute__((ext_vector_type(4)));

__device__ __forceinline__ float bf2f(unsigned short u){
  union{unsigned u; float f;} v; v.u = ((unsigned)u) << 16; return v.f;
}

__device__ __forceinline__ void gload_lds16(const void* g, void* l){
  __builtin_amdgcn_global_load_lds((const __attribute__((address_space(1))) void*)g,
                                   (__attribute__((address_space(3))) void*)l, 16, 0, 0);
}

// ---------- fp32 -> bf16 convert (vectorized, grid-stride) ----------
__global__ __launch_bounds__(256) void cvt_kernel(const float* __restrict__ in,
                                                  __hip_bfloat16* __restrict__ outp, int n4){
  int i = blockIdx.x * blockDim.x + threadIdx.x;
  int stride = gridDim.x * blockDim.x;
  for (; i < n4; i += stride){
    float4 v = reinterpret_cast<const float4*>(in)[i];
    union{ushort4 u; __hip_bfloat16 h[4];} o;
    o.h[0] = __float2bfloat16(v.x); o.h[1] = __float2bfloat16(v.y);
    o.h[2] = __float2bfloat16(v.z); o.h[3] = __float2bfloat16(v.w);
    reinterpret_cast<ushort4*>(outp)[i] = o.u;
  }
}

// ---------- router: fp64 logits, top-2, softmax weights ----------
__global__ __launch_bounds__(256) void router_kernel(
    const float* __restrict__ x, const float* __restrict__ gw,
    float* __restrict__ logits_out, int* __restrict__ tokExp,
    float* __restrict__ tokW, int* __restrict__ cnt)
{
  int wave = (blockIdx.x * blockDim.x + threadIdx.x) >> 6;
  int lane = threadIdx.x & 63;
  if (wave >= NT) return;
  const float* xr = x + (long)wave * HD;
  double acc[NE];
  #pragma unroll
  for (int e = 0; e < NE; e++) acc[e] = 0.0;
  for (int k = lane; k < HD; k += 64){
    double xv = (double)xr[k];
    #pragma unroll
    for (int e = 0; e < NE; e++) acc[e] += xv * (double)gw[e * HD + k];
  }
  #pragma unroll
  for (int e = 0; e < NE; e++){
    #pragma unroll
    for (int off = 32; off; off >>= 1) acc[e] += __shfl_down(acc[e], off, 64);
  }
  if (lane == 0){
    int e0 = 0; double v0 = acc[0];
    for (int e = 1; e < NE; e++) if (acc[e] > v0){ v0 = acc[e]; e0 = e; }
    int e1 = -1; double v1 = -1e300;
    for (int e = 0; e < NE; e++) if (e != e0 && acc[e] > v1){ v1 = acc[e]; e1 = e; }
    double ex = exp(v1 - v0);
    double s = 1.0 + ex;
    for (int e = 0; e < NE; e++) logits_out[wave * NE + e] = (float)acc[e];
    tokExp[wave * 2]     = e0; tokExp[wave * 2 + 1] = e1;
    tokW[wave * 2]       = (float)(1.0 / s);
    tokW[wave * 2 + 1]   = (float)(ex / s);
    atomicAdd(&cnt[e0], 1); atomicAdd(&cnt[e1], 1);
  }
}

// ---------- padded (256) exclusive prefix over expert counts ----------
__global__ void offsets_kernel(const int* __restrict__ cnt, int* __restrict__ padOff){
  if (threadIdx.x == 0 && blockIdx.x == 0){
    int o = 0;
    for (int e = 0; e < NE; e++){ padOff[e] = o; o += ((cnt[e] + 255) >> 8) << 8; }
    padOff[NE] = o;
  }
}

// ---------- scatter: slotTok[slot] = token*2 + which (pair id), -1 for pads ----------
__global__ __launch_bounds__(256) void scatter_kernel(
    const int* __restrict__ tokExp, const int* __restrict__ padOff, int* cursor,
    int* __restrict__ slotTok)
{
  int t = blockIdx.x * blockDim.x + threadIdx.x;
  if (t >= NT) return;
  #pragma unroll
  for (int s = 0; s < 2; s++){
    int e = tokExp[t * 2 + s];
    int pos = atomicAdd(&cursor[e], 1);
    slotTok[padOff[e] + pos] = t * 2 + s;
  }
}

// ================= 256x256 8-phase grouped GEMM =================
// C[slotrow, col] = A[gather(slotrow), :] . W[e][col, :]
// GDIV: A-gather row = pair >> GDIV (1: fc reads xb[token]; 0: proj reads hb[pair])
// EPI=0: gelu(acc+bias) -> Yout[pair][ND]; EPI=1: acc+bias -> Yout[pair][ND]
// LDS: A [2 buf][2 kk][16 subtiles][512 bf16], B same at +32768 elems. 128 KiB.
// Subtile = 16 rows x 32 k-cols; swizzle: 16B-chunk slot = chunk ^ ((r16>>1)&3)
// (2-way bank conflict = free). Applied write-side via inverse-permuted global
// source (gload_lds dest is linear), read-side via same XOR.
// Schedule per K-tile t (buf b=t&1), 4 phases:
//  p0: read (b,kk0) m0-3 + B(kk0); stage A-kk1(t+1)->b^1   [if 1<=t, t+1<NTILES]
//  p1: read (b,kk0) m4-7;          stage B-kk1(t+1)->b^1
//  p2: read (b,kk1) m0-3 + B(kk1); stage A-kk0(t+2)->b     [if t+2<NTILES]
//  p3: read (b,kk1) m4-7;          stage B-kk0(t+2)->b; vmcnt(4|0) BEFORE barrier
// vmcnt(4) before the boundary barrier => every wave's loads older than the
// newest 2 slices have landed before ANY wave proceeds -> cross-wave safe.

#define LDA(buf,kk,m) (*reinterpret_cast<const bf16x8*>(&lds[((buf)*2+(kk))*8192 + (wr*8+(m))*512 + laneF]))
#define LDB(buf,kk,n) (*reinterpret_cast<const bf16x8*>(&lds[32768 + ((buf)*2+(kk))*8192 + (wc*4+(n))*512 + laneF]))
#define STAGE_A(buf,kk,koff) do{ \
    __hip_bfloat16* d_ = &lds[((buf)*2+(kk))*8192 + w*1024]; \
    gload_lds16(aS0 + (koff), d_); \
    gload_lds16(aS1 + (koff), d_ + 512); \
  }while(0)
#define STAGE_B(buf,kk,koff) do{ \
    __hip_bfloat16* d_ = &lds[32768 + ((buf)*2+(kk))*8192 + w*1024]; \
    gload_lds16(bS0 + (koff), d_); \
    gload_lds16(bS1 + (koff), d_ + 512); \
  }while(0)
#define MFMA16(M0,A0_,A1_,A2_,A3_) do{ \
    acc[(M0)+0][0] = __builtin_amdgcn_mfma_f32_16x16x32_bf16(A0_, bv0, acc[(M0)+0][0],0,0,0); \
    acc[(M0)+1][0] = __builtin_amdgcn_mfma_f32_16x16x32_bf16(A1_, bv0, acc[(M0)+1][0],0,0,0); \
    acc[(M0)+2][0] = __builtin_amdgcn_mfma_f32_16x16x32_bf16(A2_, bv0, acc[(M0)+2][0],0,0,0); \
    acc[(M0)+3][0] = __builtin_amdgcn_mfma_f32_16x16x32_bf16(A3_, bv0, acc[(M0)+3][0],0,0,0); \
    acc[(M0)+0][1] = __builtin_amdgcn_mfma_f32_16x16x32_bf16(A0_, bv1, acc[(M0)+0][1],0,0,0); \
    acc[(M0)+1][1] = __builtin_amdgcn_mfma_f32_16x16x32_bf16(A1_, bv1, acc[(M0)+1][1],0,0,0); \
    acc[(M0)+2][1] = __builtin_amdgcn_mfma_f32_16x16x32_bf16(A2_, bv1, acc[(M0)+2][1],0,0,0); \
    acc[(M0)+3][1] = __builtin_amdgcn_mfma_f32_16x16x32_bf16(A3_, bv1, acc[(M0)+3][1],0,0,0); \
    acc[(M0)+0][2] = __builtin_amdgcn_mfma_f32_16x16x32_bf16(A0_, bv2, acc[(M0)+0][2],0,0,0); \
    acc[(M0)+1][2] = __builtin_amdgcn_mfma_f32_16x16x32_bf16(A1_, bv2, acc[(M0)+1][2],0,0,0); \
    acc[(M0)+2][2] = __builtin_amdgcn_mfma_f32_16x16x32_bf16(A2_, bv2, acc[(M0)+2][2],0,0,0); \
    acc[(M0)+3][2] = __builtin_amdgcn_mfma_f32_16x16x32_bf16(A3_, bv2, acc[(M0)+3][2],0,0,0); \
    acc[(M0)+0][3] = __builtin_amdgcn_mfma_f32_16x16x32_bf16(A0_, bv3, acc[(M0)+0][3],0,0,0); \
    acc[(M0)+1][3] = __builtin_amdgcn_mfma_f32_16x16x32_bf16(A1_, bv3, acc[(M0)+1][3],0,0,0); \
    acc[(M0)+2][3] = __builtin_amdgcn_mfma_f32_16x16x32_bf16(A2_, bv3, acc[(M0)+3][3],0,0,0); \
    acc[(M0)+3][3] = __builtin_amdgcn_mfma_f32_16x16x32_bf16(A3_, bv3, acc[(M0)+3][3],0,0,0); \
  }while(0)

// NOTE: the line above had a typo risk; define correctly below (undef+redef).
#undef MFMA16
#define MFMA16(M0,A0_,A1_,A2_,A3_) do{ \
    acc[(M0)+0][0] = __builtin_amdgcn_mfma_f32_16x16x32_bf16(A0_, bv0, acc[(M0)+0][0],0,0,0); \
    acc[(M0)+1][0] = __builtin_amdgcn_mfma_f32_16x16x32_bf16(A1_, bv0, acc[(M0)+1][0],0,0,0); \
    acc[(M0)+2][0] = __builtin_amdgcn_mfma_f32_16x16x32_bf16(A2_, bv0, acc[(M0)+2][0],0,0,0); \
    acc[(M0)+3][0] = __builtin_amdgcn_mfma_f32_16x16x32_bf16(A3_, bv0, acc[(M0)+3][0],0,0,0); \
    acc[(M0)+0][1] = __builtin_amdgcn_mfma_f32_16x16x32_bf16(A0_, bv1, acc[(M0)+0][1],0,0,0); \
    acc[(M0)+1][1] = __builtin_amdgcn_mfma_f32_16x16x32_bf16(A1_, bv1, acc[(M0)+1][1],0,0,0); \
    acc[(M0)+2][1] = __builtin_amdgcn_mfma_f32_16x16x32_bf16(A2_, bv1, acc[(M0)+2][1],0,0,0); \
    acc[(M0)+3][1] = __builtin_amdgcn_mfma_f32_16x16x32_bf16(A3_, bv1, acc[(M0)+3][1],0,0,0); \
    acc[(M0)+0][2] = __builtin_amdgcn_mfma_f32_16x16x32_bf16(A0_, bv2, acc[(M0)+0][2],0,0,0); \
    acc[(M0)+1][2] = __builtin_amdgcn_mfma_f32_16x16x32_bf16(A1_, bv2, acc[(M0)+1][2],0,0,0); \
    acc[(M0)+2][2] = __builtin_amdgcn_mfma_f32_16x16x32_bf16(A2_, bv2, acc[(M0)+2][2],0,0,0); \
    acc[(M0)+3][2] = __builtin_amdgcn_mfma_f32_16x16x32_bf16(A3_, bv2, acc[(M0)+3][2],0,0,0); \
    acc[(M0)+0][3] = __builtin_amdgcn_mfma_f32_16x16x32_bf16(A0_, bv3, acc[(M0)+0][3],0,0,0); \
    acc[(M0)+1][3] = __builtin_amdgcn_mfma_f32_16x16x32_bf16(A1_, bv3, acc[(M0)+1][3],0,0,0); \
    acc[(M0)+2][3] = __builtin_amdgcn_mfma_f32_16x16x32_bf16(A2_, bv3, acc[(M0)+2][3],0,0,0); \
    acc[(M0)+3][3] = __builtin_amdgcn_mfma_f32_16x16x32_bf16(A3_, bv3, acc[(M0)+3][3],0,0,0); \
  }while(0)

template<int GDIV, int EPI, int ND, int KD>
__global__ __launch_bounds__(512, 2) void moe_gemm8(
    const __hip_bfloat16* __restrict__ A,
    const __hip_bfloat16* __restrict__ W,
    const float* __restrict__ bias,
    const int* __restrict__ slotTok,
    const int* __restrict__ padOff,
    __hip_bfloat16* __restrict__ Yout)
{
  __shared__ __align__(16) __hip_bfloat16 lds[65536];  // 128 KiB
  const int rb = blockIdx.y;
  if (rb * 256 >= padOff[NE]) return;
  const int cb = blockIdx.x;
  int e = 0;
  #pragma unroll
  for (int i = 1; i < NE; i++) if (rb * 256 >= padOff[i]) e = i;

  const int tid  = threadIdx.x;
  const int lane = tid & 63;
  const int w    = tid >> 6;   // 0..7
  const int wr   = w >> 2;     // 0..1 (M half)
  const int wc   = w & 3;      // 0..3 (N quarter)

  // ---- staging addresses (wave w stages subtiles 2w,2w+1 = rows 32w..32w+31)
  const int r16s = lane >> 2;
  const int cgs  = (lane & 3) ^ ((r16s >> 1) & 3);   // inverse swizzle on global k-chunk
  const int rowA = rb * 256 + 32 * w + r16s;
  int pr0 = slotTok[rowA];      long ga0 = pr0 < 0 ? 0 : (pr0 >> GDIV);
  int pr1 = slotTok[rowA + 16]; long ga1 = pr1 < 0 ? 0 : (pr1 >> GDIV);
  const __hip_bfloat16* aS0 = A + ga0 * (long)KD + cgs * 8;
  const __hip_bfloat16* aS1 = A + ga1 * (long)KD + cgs * 8;
  const long rowB = (long)cb * 256 + 32 * w + r16s;
  const __hip_bfloat16* bS0 = W + (long)e * ND * KD + rowB * KD + cgs * 8;
  const __hip_bfloat16* bS1 = bS0 + 16 * (long)KD;

  // ---- fragment read lane offset (swizzled)
  const int r16f = lane & 15;
  const int chf  = lane >> 4;
  const int laneF = r16f * 32 + (chf ^ ((r16f >> 1) & 3)) * 8;

  f32x4 acc[8][4] = {};
  bf16x8 bv0, bv1, bv2, bv3;

  constexpr int NTILES = KD / 64;

  // ---- prologue: stage tiles 0 and 1 fully (16 loads/wave)
  STAGE_A(0,0,0);   STAGE_B(0,0,0);
  STAGE_A(0,1,32);  STAGE_B(0,1,32);
  STAGE_A(1,0,64);  STAGE_B(1,0,64);
  STAGE_A(1,1,96);  STAGE_B(1,1,96);
  asm volatile("s_waitcnt vmcnt(8)" ::: "memory");   // tile 0 fully resident
  __builtin_amdgcn_s_barrier();

  for (int t = 0; t < NTILES; ++t){
    const int b = t & 1;
    const bool s01 = (t >= 1) && (t + 1 < NTILES);
    const bool s23 = (t + 2 < NTILES);
    const long ko01 = (long)(t + 1) * 64 + 32;
    const long ko23 = (long)(t + 2) * 64;
    // ---- phase 0: (b,kk0) m0-3
    {
      bf16x8 a0 = LDA(b,0,0), a1 = LDA(b,0,1), a2 = LDA(b,0,2), a3 = LDA(b,0,3);
      bv0 = LDB(b,0,0); bv1 = LDB(b,0,1); bv2 = LDB(b,0,2); bv3 = LDB(b,0,3);
      if (s01){ STAGE_A(b^1,1,ko01); }
      __builtin_amdgcn_s_barrier();
      asm volatile("s_waitcnt lgkmcnt(0)" ::: "memory");
      __builtin_amdgcn_s_setprio(1);
      MFMA16(0, a0, a1, a2, a3);
      __builtin_amdgcn_s_setprio(0);
      __builtin_amdgcn_s_barrier();
    }
    // ---- phase 1: (b,kk0) m4-7
    {
      bf16x8 a0 = LDA(b,0,4), a1 = LDA(b,0,5), a2 = LDA(b,0,6), a3 = LDA(b,0,7);
      if (s01){ STAGE_B(b^1,1,ko01); }
      __builtin_amdgcn_s_barrier();
      asm volatile("s_waitcnt lgkmcnt(0)" ::: "memory");
      __builtin_amdgcn_s_setprio(1);
      MFMA16(4, a0, a1, a2, a3);
      __builtin_amdgcn_s_setprio(0);
      __builtin_amdgcn_s_barrier();
    }
    // ---- phase 2: (b,kk1) m0-3
    {
      bf16x8 a0 = LDA(b,1,0), a1 = LDA(b,1,1), a2 = LDA(b,1,2), a3 = LDA(b,1,3);
      bv0 = LDB(b,1,0); bv1 = LDB(b,1,1); bv2 = LDB(b,1,2); bv3 = LDB(b,1,3);
      if (s23){ STAGE_A(b,0,ko23); }
      __builtin_amdgcn_s_barrier();
      asm volatile("s_waitcnt lgkmcnt(0)" ::: "memory");
      __builtin_amdgcn_s_setprio(1);
      MFMA16(0, a0, a1, a2, a3);
      __builtin_amdgcn_s_setprio(0);
      __builtin_amdgcn_s_barrier();
    }
    // ---- phase 3: (b,kk1) m4-7; counted vmcnt BEFORE boundary barrier
    {
      bf16x8 a0 = LDA(b,1,4), a1 = LDA(b,1,5), a2 = LDA(b,1,6), a3 = LDA(b,1,7);
      if (s23){ STAGE_B(b,0,ko23); }
      __builtin_amdgcn_s_barrier();
      asm volatile("s_waitcnt lgkmcnt(0)" ::: "memory");
      __builtin_amdgcn_s_setprio(1);
      MFMA16(4, a0, a1, a2, a3);
      __builtin_amdgcn_s_setprio(0);
      if (s23) asm volatile("s_waitcnt vmcnt(4)" ::: "memory");
      else     asm volatile("s_waitcnt vmcnt(0)" ::: "memory");
      __builtin_amdgcn_s_barrier();
    }
  }

  // ---- epilogue: C layout col=lane&15, row=(lane>>4)*4+reg
  const int colBase = cb * 256 + wc * 64 + (lane & 15);
  const int rowQ = (lane >> 4) * 4;
  float bb[4];
  #pragma unroll
  for (int n = 0; n < 4; n++) bb[n] = bias[(long)e * ND + colBase + n * 16];
  #pragma unroll
  for (int m = 0; m < 8; m++){
    const int grow = rb * 256 + wr * 128 + m * 16 + rowQ;
    #pragma unroll
    for (int r = 0; r < 4; r++){
      const int pr = slotTok[grow + r];
      if (pr >= 0){
        #pragma unroll
        for (int n = 0; n < 4; n++){
          float v = acc[m][n][r] + bb[n];
          if (EPI == 0){
            v = 0.5f * v * (1.0f + erff(v * 0.70710678118654752f));  // exact gelu
          }
          Yout[(long)pr * ND + colBase + n * 16] = __float2bfloat16(v);
        }
      }
    }
  }
}

// ---------- combine: out[t] = w0*y[pair 2t] + w1*y[pair 2t+1] ----------
__global__ __launch_bounds__(256) void combine_kernel(
    const __hip_bfloat16* __restrict__ yb, const float* __restrict__ tokW,
    float* __restrict__ outp)
{
  const int t  = blockIdx.x;
  const int c0 = threadIdx.x * 8;
  const float w0 = tokW[t * 2], w1 = tokW[t * 2 + 1];
  const ushort4* p0 = reinterpret_cast<const ushort4*>(yb + (long)(2 * t) * HD + c0);
  const ushort4* p1 = reinterpret_cast<const ushort4*>(yb + (long)(2 * t + 1) * HD + c0);
  float4 o[2];
  #pragma unroll
  for (int h = 0; h < 2; h++){
    ushort4 a = p0[h], b = p1[h];
    o[h].x = w0 * bf2f(a.x) + w1 * bf2f(b.x);
    o[h].y = w0 * bf2f(a.y) + w1 * bf2f(b.y);
    o[h].z = w0 * bf2f(a.z) + w1 * bf2f(b.z);
    o[h].w = w0 * bf2f(a.w) + w1 * bf2f(b.w);
  }
  float4* po = reinterpret_cast<float4*>(outp + (long)t * HD + c0);
  po[0] = o[0]; po[1] = o[1];
}

extern "C" void kernel_launch(void* const* d_in, const int* in_sizes, int n_in,
                              void* d_out, int out_size, void* d_ws, size_t ws_size,
                              hipStream_t stream)
{
  (void)in_sizes; (void)n_in; (void)out_size; (void)ws_size;
  const float* x     = (const float*)d_in[0];
  const float* gw    = (const float*)d_in[1];
  const float* wfc   = (const float*)d_in[2];
  const float* bfc   = (const float*)d_in[3];
  const float* wproj = (const float*)d_in[4];
  const float* bproj = (const float*)d_in[5];
  float* outp   = (float*)d_out;
  float* logits = outp + (size_t)NT * HD;

  char* ws = (char*)d_ws;
  size_t off = 0;
  auto alloc = [&](size_t b){ void* p = ws + off; off += (b + 255) & ~(size_t)255; return p; };

  // region0: xb (fc input, NT rows) then yb (proj output, 2*NT pair rows) — disjoint lifetimes
  char* region0 = (char*)alloc((size_t)NT * 2 * HD * 2);                  // 67 MB
  __hip_bfloat16* xb = (__hip_bfloat16*)region0;
  __hip_bfloat16* yb = (__hip_bfloat16*)region0;
  __hip_bfloat16* hb = (__hip_bfloat16*)alloc((size_t)NT * 2 * ID * 2);   // 134 MB (pair space)
  __hip_bfloat16* wB = (__hip_bfloat16*)alloc((size_t)NE * ID * HD * 2);  // 134 MB (reused fc->proj)
  int*   slotTok = (int*)alloc(MAXSLOT * 4);
  int*   tokExp  = (int*)alloc(NT * 2 * 4);
  float* tokW    = (float*)alloc(NT * 2 * 4);
  int*   meta    = (int*)alloc(256);
  int* cnt = meta; int* cursor = meta + 8; int* padOff = meta + 16;

  hipMemsetAsync(meta, 0, 256, stream);
  hipMemsetAsync(slotTok, 0xFF, MAXSLOT * 4, stream);

  cvt_kernel<<<2048, 256, 0, stream>>>(x, xb, NT * HD / 4);
  router_kernel<<<NT / 4, 256, 0, stream>>>(x, gw, logits, tokExp, tokW, cnt);
  offsets_kernel<<<1, 64, 0, stream>>>(cnt, padOff);
  scatter_kernel<<<NT / 256, 256, 0, stream>>>(tokExp, padOff, cursor, slotTok);

  cvt_kernel<<<2048, 256, 0, stream>>>(wfc, wB, NE * ID * HD / 4);
  moe_gemm8<1, 0, ID, HD><<<dim3(ID / 256, MAXRB), 512, 0, stream>>>(xb, wB, bfc, slotTok, padOff, hb);
  cvt_kernel<<<2048, 256, 0, stream>>>(wproj, wB, NE * HD * ID / 4);
  moe_gemm8<0, 1, HD, ID><<<dim3(HD / 256, MAXRB), 512, 0, stream>>>(hb, wB, bproj, slotTok, padOff, yb);

  combine_kernel<<<NT, 256, 0, stream>>>(yb, tokW, outp);
}